// Round 14
// baseline (13601.779 us; speedup 1.0000x reference)
//
#include <hip/hip_runtime.h>
#include <math.h>

// ESN reservoir, persistent kernel, round 14.
// h_t = tanh(x_t Win^T + h_{t-1} W^T); out_t = h_t Wout^T + b
//
// r13 (10.49ms, matched prediction): k<1024 W in 128KB LDS f16 + fdot2;
// k>=1024 fp32 W from L2. Counters showed SQ_LDS_BANK_CONFLICT x5.6: the
// fdot2 half used 32B lane stride (2-way conflict per 8-lane phase).
// r14 = r13 + three micro-fixes, structure untouched:
//  1. conflict-free LDS reads: lane's k-slice = granules {lane, 64+lane}
//     (16B stride, the measured conflict-free b128 pattern). k-partition
//     across lanes is arbitrary -> numerics unchanged.
//  2. W chunk c=2 register-prefetch issued BEFORE gate+stage (hides ~1us of
//     the 1.9us L2-W stream under the exchange; +64 VGPR, within budget).
//  3. v_pk_fma_f32 via float2 elementwise-fma for the fp32-W half
//     (batches packed: 16 fma -> 8 pk_fma per row-granule).
// All spins bounded: worst case wrong answer, never a hang.

#define RDIM   2048
#define BATCH  16
#define TSTEPS 2048
#define NIN    3
#define NOUT   3
#define NBLK   256
#define NTHR   512
#define KHALF  1024                          // k<KHALF from LDS-f16 W

#define HB_U32    ((BATCH * RDIM) / 2)       // 16384 dwords (packed f16x2)
#define OFF_H0    0
#define OFF_H1    (HB_U32)
#define OFF_FLAGS (2 * HB_U32)               // 256 dwords
#define WS_USED   (OFF_FLAGS + 256)
#define WLDS_DW   (64 * (KHALF / 2))         // 32768 dwords = 128 KB
#define SPIN_MAX  (1L << 20)

#define CPOL_SC0_SC1 0x11                    // UC: read at coherence point

typedef _Float16 half2v __attribute__((ext_vector_type(2)));
typedef float    float2v __attribute__((ext_vector_type(2)));
union HU { unsigned u; half2v h; };

__device__ __forceinline__ void load_lds16(const void* g, void* l) {
    __builtin_amdgcn_global_load_lds(
        (const __attribute__((address_space(1))) void*)g,
        (__attribute__((address_space(3))) void*)l, 16, 0, CPOL_SC0_SC1);
}

__device__ __forceinline__ unsigned sysld(const unsigned* p) {
    return __hip_atomic_load(p, __ATOMIC_RELAXED, __HIP_MEMORY_SCOPE_SYSTEM);
}
__device__ __forceinline__ void sysst(unsigned* p, unsigned v) {
    __hip_atomic_store(p, v, __ATOMIC_RELAXED, __HIP_MEMORY_SCOPE_SYSTEM);
}

__device__ __forceinline__ float f16lo(unsigned u) { HU c; c.u = u; return (float)c.h.x; }
__device__ __forceinline__ float f16hi(unsigned u) { HU c; c.u = u; return (float)c.h.y; }
__device__ __forceinline__ unsigned packf16(float a, float b) {
    HU c; c.h.x = (_Float16)a; c.h.y = (_Float16)b; return c.u;
}
__device__ __forceinline__ float f16s(unsigned short s) {
    union { unsigned short u; _Float16 h; } c; c.u = s; return (float)c.h;
}

// 8-element f16 dot: wq . hq + c, fp32 accumulate (v_dot2_f32_f16)
__device__ __forceinline__ float dot8(uint4 wq, uint4 hq, float c) {
#if __has_builtin(__builtin_amdgcn_fdot2)
    HU a, b;
    a.u = wq.x; b.u = hq.x; c = __builtin_amdgcn_fdot2(a.h, b.h, c, false);
    a.u = wq.y; b.u = hq.y; c = __builtin_amdgcn_fdot2(a.h, b.h, c, false);
    a.u = wq.z; b.u = hq.z; c = __builtin_amdgcn_fdot2(a.h, b.h, c, false);
    a.u = wq.w; b.u = hq.w; c = __builtin_amdgcn_fdot2(a.h, b.h, c, false);
#else
    c += f16lo(wq.x) * f16lo(hq.x) + f16hi(wq.x) * f16hi(hq.x);
    c += f16lo(wq.y) * f16lo(hq.y) + f16hi(wq.y) * f16hi(hq.y);
    c += f16lo(wq.z) * f16lo(hq.z) + f16hi(wq.z) * f16hi(hq.z);
    c += f16lo(wq.w) * f16lo(hq.w) + f16hi(wq.w) * f16hi(hq.w);
#endif
    return c;
}

extern "C" __global__ void __launch_bounds__(NTHR, 1) esn_persist(
    const float* __restrict__ W,       // [R,R] fp32 (d_in: L2-resident)
    const float* __restrict__ Win,     // [R,3]
    const float* __restrict__ x,       // [B,T,3]
    const float* __restrict__ Wout,    // [3,R]
    const float* __restrict__ bout,    // [3]
    unsigned* hb0,                     // [B][R/2] packed f16x2
    unsigned* hb1,
    unsigned* flags,                   // [256]
    float* __restrict__ out)           // [B,T,3]
{
    __shared__ unsigned hs_dw[2048];            // 8 KB: [2 batches][1024 dwords]
    __shared__ float red[8][544];               // transpose-reduce scratch
    __shared__ float hblk[64][2];               // 64 rows x 2 batches
    extern __shared__ unsigned wlds[];          // 128 KB: W[64 rows][k<1024] f16x2

    const int tid  = threadIdx.x;
    const int lane = tid & 63;
    const int w    = tid >> 6;                  // wave 0..7
    const int blk  = blockIdx.x;
    const int rg   = blk & 31;                  // rows rg*64..+64
    const int g    = blk >> 5;                  // batches g*2..+2
    const int rbase = rg * 64 + w * 8;          // wave's 8 rows
    const int b0    = g * 2;

    const float4* W4 = (const float4*)W;        // row stride 512 float4

    // ---- one-time: convert W rows, k<1024 -> LDS packed f16x2 ----
#pragma unroll
    for (int i = 0; i < WLDS_DW / NTHR; ++i) {  // 64 iters
        const int idx = i * NTHR + tid;         // r*512 + kk
        const int r   = idx >> 9;
        const int kk  = idx & 511;
        const float2 v = ((const float2*)(W + (size_t)(rg * 64 + r) * RDIM))[kk];
        wlds[idx] = packf16(v.x, v.y);
    }
    __syncthreads();

    for (int t = 0; t <= TSTEPS; ++t) {
        const unsigned* hprev = (t & 1) ? hb1 : hb0;
        unsigned*       hnext = (t & 1) ? hb0 : hb1;
        const unsigned  tgt   = (unsigned)t;

        // ---- W chunk c=2 register prefetch: overlaps gate + stage ----
        float4 wpre[8][2];
        if (t < TSTEPS) {
#pragma unroll
            for (int rr = 0; rr < 8; ++rr) {
                const float4* Wp = W4 + (size_t)(rbase + rr) * (RDIM / 4)
                                 + (128 + lane) * 2;
                wpre[rr][0] = Wp[0];
                wpre[rr][1] = Wp[1];
            }
        }

        // ---- one-hop gate: all 32 producers of my group at >= t ----
        if (t > 0 && w == 0) {
            long spins = 0;
            for (;;) {
                unsigned vv = (lane < 32) ? sysld(&flags[g * 32 + lane]) : tgt;
                if (__all((int)(vv >= tgt))) break;
                if (spins > 64) __builtin_amdgcn_s_sleep(2);  // fast-poll first
                if (++spins > SPIN_MAX) break;   // never hang
            }
        }
        __syncthreads();

        // ---- stage h[b0..b0+1][:] (8 KB) -> LDS, r8-exact ----
        {
            const int gran = w * 64 + lane;              // 16B granule 0..511
            load_lds16(hprev + (size_t)g * 2048 + (size_t)gran * 4,
                       (char*)hs_dw + (size_t)(w * 64) * 16);
        }
        __syncthreads();   // staging complete (drains vmcnt)

        if (t < TSTEPS) {
            float2v acc2[8];                    // (b0, b1) packed
#pragma unroll
            for (int r = 0; r < 8; ++r) acc2[r] = (float2v){0.f, 0.f};

            const uint4* h4 = (const uint4*)hs_dw;   // b0: 0..255, b1: 256..511

            // ---- k < 1024: W from LDS (f16), fdot2; CONFLICT-FREE 16B
            //      stride: lane's granules {lane, 64+lane} ----
            {
                const uint4* w4p = (const uint4*)wlds;
                uint4 hA0 = h4[lane];                 // b0, k = 8*lane..+8
                uint4 hA1 = h4[64 + lane];            // b0, k = 512+8*lane..+8
                uint4 hB0 = h4[256 + lane];           // b1
                uint4 hB1 = h4[256 + 64 + lane];
#pragma unroll
                for (int rr = 0; rr < 8; ++rr) {
                    const int wb = (w * 8 + rr) * 128;
                    uint4 w0 = w4p[wb + lane];
                    uint4 w1 = w4p[wb + 64 + lane];
                    acc2[rr].x = dot8(w0, hA0, acc2[rr].x);
                    acc2[rr].x = dot8(w1, hA1, acc2[rr].x);
                    acc2[rr].y = dot8(w0, hB0, acc2[rr].y);
                    acc2[rr].y = dot8(w1, hB1, acc2[rr].y);
                }
            }

            // ---- k >= 1024: fp32 W (c=2 from regs, c=3 from L2), pk_fma ----
#pragma unroll
            for (int c = 2; c < 4; ++c) {
                const int gr = c * 64 + lane;        // granule (8 k), 16B stride
                uint4 q0 = h4[gr];                   // batch b0
                uint4 q1 = h4[256 + gr];             // batch b0+1
                float2v h0 = {f16lo(q0.x), f16lo(q1.x)};
                float2v h1 = {f16hi(q0.x), f16hi(q1.x)};
                float2v h2 = {f16lo(q0.y), f16lo(q1.y)};
                float2v h3 = {f16hi(q0.y), f16hi(q1.y)};
                float2v h4p = {f16lo(q0.z), f16lo(q1.z)};
                float2v h5 = {f16hi(q0.z), f16hi(q1.z)};
                float2v h6 = {f16lo(q0.w), f16lo(q1.w)};
                float2v h7 = {f16hi(q0.w), f16hi(q1.w)};
#pragma unroll
                for (int rr = 0; rr < 8; ++rr) {
                    float4 w0, w1;
                    if (c == 2) { w0 = wpre[rr][0]; w1 = wpre[rr][1]; }
                    else {
                        const float4* Wp = W4 + (size_t)(rbase + rr) * (RDIM / 4) + gr * 2;
                        w0 = Wp[0];
                        w1 = Wp[1];
                    }
#define PKF(wv, hp) acc2[rr] = __builtin_elementwise_fma((float2v){wv, wv}, hp, acc2[rr])
                    PKF(w0.x, h0); PKF(w0.y, h1); PKF(w0.z, h2); PKF(w0.w, h3);
                    PKF(w1.x, h4p); PKF(w1.y, h5); PKF(w1.z, h6); PKF(w1.w, h7);
#undef PKF
                }
            }

            // ---- reduce: fold 32, swizzled transpose, sum 32 partials ----
            float v[16];
#pragma unroll
            for (int i = 0; i < 16; ++i) {
                float a = (i & 1) ? acc2[i >> 1].y : acc2[i >> 1].x;
                v[i] = a + __shfl_xor(a, 32, 64);
            }
            if (lane < 32) {
#pragma unroll
                for (int i = 0; i < 16; ++i)
                    red[w][lane * 17 + ((i + lane) & 15)] = v[i];
            }
            __syncthreads();
            if (lane < 16) {
                float s = 0.f;
#pragma unroll
                for (int l = 0; l < 32; ++l)
                    s += red[w][l * 17 + ((lane + l) & 15)];
                const int r   = lane >> 1;          // 0..7
                const int b   = lane & 1;
                const int row = rbase + r;
                const int bg  = b0 + b;
                float pre = s;
#pragma unroll
                for (int c = 0; c < NIN; ++c)
                    pre += Win[row * NIN + c] * x[((size_t)bg * TSTEPS + t) * NIN + c];
                hblk[w * 8 + r][b] = tanhf(pre);
            }
            __syncthreads();   // hblk complete

            // ---- write h_new strips (UC) + flag, r8-exact discipline ----
            if (w == 0) {
                const int b = lane >> 5;            // 0..1
                const int j = lane & 31;            // dword within 64-row strip
                sysst(&hnext[(size_t)(b0 + b) * (RDIM / 2) + rg * 32 + j],
                      packf16(hblk[2 * j][b], hblk[2 * j + 1][b]));
                __builtin_amdgcn_s_waitcnt(0);      // strips visible first
            }
            __syncthreads();
            if (tid == 0) sysst(&flags[g * 32 + rg], (unsigned)(t + 1));
        }

        // ---- projection of h_{t-1}-state (in hs) by rotating block ----
        if (t > 0 && rg == ((t - 1) & 31)) {
            const unsigned short* hsv = (const unsigned short*)hs_dw;
            const int o = t - 1;
            if (w < 6) {
                const int b = w / NOUT;             // 0..1
                const int k = w % NOUT;             // 0..2
                float a = 0.f;
#pragma unroll
                for (int j = 0; j < 32; ++j) {
                    const int r = j * 64 + lane;
                    a += f16s(hsv[b * RDIM + r]) * Wout[k * RDIM + r];
                }
#pragma unroll
                for (int off = 32; off >= 1; off >>= 1)
                    a += __shfl_xor(a, off, 64);
                if (lane == 0)
                    out[((size_t)(b0 + b) * TSTEPS + o) * NOUT + k] = a + bout[k];
            }
        }
    }
}

extern "C" void kernel_launch(void* const* d_in, const int* in_sizes, int n_in,
                              void* d_out, int out_size, void* d_ws, size_t ws_size,
                              hipStream_t stream) {
    const float* x    = (const float*)d_in[0];
    const float* Win  = (const float*)d_in[1];
    const float* W    = (const float*)d_in[2];
    const float* Wout = (const float*)d_in[3];
    const float* bout = (const float*)d_in[4];
    float* out = (float*)d_out;

    unsigned* wsu   = (unsigned*)d_ws;
    unsigned* hb0   = wsu + OFF_H0;
    unsigned* hb1   = wsu + OFF_H1;
    unsigned* flags = wsu + OFF_FLAGS;

    // zero h buffers + flags (~132 KB)
    hipMemsetAsync(d_ws, 0, (size_t)WS_USED * sizeof(unsigned), stream);

    // allow 128 KB dynamic LDS (idempotent; same work every call)
    hipFuncSetAttribute((const void*)esn_persist,
                        hipFuncAttributeMaxDynamicSharedMemorySize, 131072);

    void* args[] = {(void*)&W, (void*)&Win, (void*)&x, (void*)&Wout, (void*)&bout,
                    (void*)&hb0, (void*)&hb1, (void*)&flags, (void*)&out};
    hipError_t e = hipLaunchCooperativeKernel((const void*)esn_persist,
                                              dim3(NBLK), dim3(NTHR),
                                              args, 131072, stream);
    if (e != hipSuccess) {
        // Fallback: plain launch (256 blocks, 1/CU with 154KB LDS -> all
        // co-resident; bounded spins guarantee no hang regardless).
        esn_persist<<<dim3(NBLK), dim3(NTHR), 131072, stream>>>(
            W, Win, x, Wout, bout, hb0, hb1, flags, out);
    }
}

// Round 15
// 11290.874 us; speedup vs baseline: 1.2047x; 1.2047x over previous
//
#include <hip/hip_runtime.h>
#include <math.h>

// ESN reservoir, persistent kernel, round 15.
// h_t = tanh(x_t Win^T + h_{t-1} W^T); out_t = h_t Wout^T + b
//
// r13 = 10.49ms (matched model). r14 bundled 3 changes -> regressed via
// register-pressure (W prefetch held 64 VGPRs across the whole K-loop);
// its conflict fix DID work (SQ_LDS_BANK_CONFLICT 4.09e8 -> 7.3e7).
// r15 = r13 verbatim + ONLY the conflict fix:
//   fdot2 half reads lane granules {lane, 64+lane} (16B stride, measured
//   conflict-free b128 pattern) for both h and LDS-W. k-partition across
//   lanes is arbitrary -> numerics identical to r13 (absmax 0.0039).
// Structure: k<1024 W in 128KB dynamic LDS as f16x2 (converted once),
// fdot2 compute; k>=1024 fp32 W streamed from d_in/L2 (L2-resident);
// 8KB h exchange per block via UC global_load_lds; one-hop 32-flag gate
// with fast-poll; rotating projection block; bounded spins (never hangs).

#define RDIM   2048
#define BATCH  16
#define TSTEPS 2048
#define NIN    3
#define NOUT   3
#define NBLK   256
#define NTHR   512
#define KHALF  1024                          // k<KHALF from LDS-f16 W

#define HB_U32    ((BATCH * RDIM) / 2)       // 16384 dwords (packed f16x2)
#define OFF_H0    0
#define OFF_H1    (HB_U32)
#define OFF_FLAGS (2 * HB_U32)               // 256 dwords
#define WS_USED   (OFF_FLAGS + 256)
#define WLDS_DW   (64 * (KHALF / 2))         // 32768 dwords = 128 KB
#define SPIN_MAX  (1L << 20)

#define CPOL_SC0_SC1 0x11                    // UC: read at coherence point

typedef _Float16 half2v __attribute__((ext_vector_type(2)));
union HU { unsigned u; half2v h; };

__device__ __forceinline__ void load_lds16(const void* g, void* l) {
    __builtin_amdgcn_global_load_lds(
        (const __attribute__((address_space(1))) void*)g,
        (__attribute__((address_space(3))) void*)l, 16, 0, CPOL_SC0_SC1);
}

__device__ __forceinline__ unsigned sysld(const unsigned* p) {
    return __hip_atomic_load(p, __ATOMIC_RELAXED, __HIP_MEMORY_SCOPE_SYSTEM);
}
__device__ __forceinline__ void sysst(unsigned* p, unsigned v) {
    __hip_atomic_store(p, v, __ATOMIC_RELAXED, __HIP_MEMORY_SCOPE_SYSTEM);
}

__device__ __forceinline__ float f16lo(unsigned u) { HU c; c.u = u; return (float)c.h.x; }
__device__ __forceinline__ float f16hi(unsigned u) { HU c; c.u = u; return (float)c.h.y; }
__device__ __forceinline__ unsigned packf16(float a, float b) {
    HU c; c.h.x = (_Float16)a; c.h.y = (_Float16)b; return c.u;
}
__device__ __forceinline__ float f16s(unsigned short s) {
    union { unsigned short u; _Float16 h; } c; c.u = s; return (float)c.h;
}

// 8-element f16 dot: wq . hq + c, fp32 accumulate (v_dot2_f32_f16)
__device__ __forceinline__ float dot8(uint4 wq, uint4 hq, float c) {
#if __has_builtin(__builtin_amdgcn_fdot2)
    HU a, b;
    a.u = wq.x; b.u = hq.x; c = __builtin_amdgcn_fdot2(a.h, b.h, c, false);
    a.u = wq.y; b.u = hq.y; c = __builtin_amdgcn_fdot2(a.h, b.h, c, false);
    a.u = wq.z; b.u = hq.z; c = __builtin_amdgcn_fdot2(a.h, b.h, c, false);
    a.u = wq.w; b.u = hq.w; c = __builtin_amdgcn_fdot2(a.h, b.h, c, false);
#else
    c += f16lo(wq.x) * f16lo(hq.x) + f16hi(wq.x) * f16hi(hq.x);
    c += f16lo(wq.y) * f16lo(hq.y) + f16hi(wq.y) * f16hi(hq.y);
    c += f16lo(wq.z) * f16lo(hq.z) + f16hi(wq.z) * f16hi(hq.z);
    c += f16lo(wq.w) * f16lo(hq.w) + f16hi(wq.w) * f16hi(hq.w);
#endif
    return c;
}

extern "C" __global__ void __launch_bounds__(NTHR, 1) esn_persist(
    const float* __restrict__ W,       // [R,R] fp32 (d_in: L2-resident)
    const float* __restrict__ Win,     // [R,3]
    const float* __restrict__ x,       // [B,T,3]
    const float* __restrict__ Wout,    // [3,R]
    const float* __restrict__ bout,    // [3]
    unsigned* hb0,                     // [B][R/2] packed f16x2
    unsigned* hb1,
    unsigned* flags,                   // [256]
    float* __restrict__ out)           // [B,T,3]
{
    __shared__ unsigned hs_dw[2048];            // 8 KB: [2 batches][1024 dwords]
    __shared__ float red[8][544];               // transpose-reduce scratch
    __shared__ float hblk[64][2];               // 64 rows x 2 batches
    extern __shared__ unsigned wlds[];          // 128 KB: W[64 rows][k<1024] f16x2

    const int tid  = threadIdx.x;
    const int lane = tid & 63;
    const int w    = tid >> 6;                  // wave 0..7
    const int blk  = blockIdx.x;
    const int rg   = blk & 31;                  // rows rg*64..+64
    const int g    = blk >> 5;                  // batches g*2..+2
    const int rbase = rg * 64 + w * 8;          // wave's 8 rows
    const int b0    = g * 2;

    const float4* W4 = (const float4*)W;        // row stride 512 float4

    // ---- one-time: convert W rows, k<1024 -> LDS packed f16x2 ----
#pragma unroll
    for (int i = 0; i < WLDS_DW / NTHR; ++i) {  // 64 iters
        const int idx = i * NTHR + tid;         // r*512 + kk
        const int r   = idx >> 9;
        const int kk  = idx & 511;
        const float2 v = ((const float2*)(W + (size_t)(rg * 64 + r) * RDIM))[kk];
        wlds[idx] = packf16(v.x, v.y);
    }
    __syncthreads();

    for (int t = 0; t <= TSTEPS; ++t) {
        const unsigned* hprev = (t & 1) ? hb1 : hb0;
        unsigned*       hnext = (t & 1) ? hb0 : hb1;
        const unsigned  tgt   = (unsigned)t;

        // ---- one-hop gate: all 32 producers of my group at >= t ----
        if (t > 0 && w == 0) {
            long spins = 0;
            for (;;) {
                unsigned vv = (lane < 32) ? sysld(&flags[g * 32 + lane]) : tgt;
                if (__all((int)(vv >= tgt))) break;
                if (spins > 64) __builtin_amdgcn_s_sleep(2);  // fast-poll first
                if (++spins > SPIN_MAX) break;   // never hang
            }
        }
        __syncthreads();

        // ---- stage h[b0..b0+1][:] (8 KB) -> LDS, r8-exact ----
        {
            const int gran = w * 64 + lane;              // 16B granule 0..511
            load_lds16(hprev + (size_t)g * 2048 + (size_t)gran * 4,
                       (char*)hs_dw + (size_t)(w * 64) * 16);
        }
        __syncthreads();   // staging complete (drains vmcnt)

        if (t < TSTEPS) {
            float acc[8][2];
#pragma unroll
            for (int r = 0; r < 8; ++r) { acc[r][0] = 0.f; acc[r][1] = 0.f; }

            const uint4* h4 = (const uint4*)hs_dw;   // b0: 0..255, b1: 256..511

            // ---- k < 1024: W from LDS (f16), fdot2 — CONFLICT-FREE:
            //      lane's granules {lane, 64+lane} (16B stride) ----
            {
                const uint4* w4p = (const uint4*)wlds;
                uint4 hA0 = h4[lane];                 // b0, k = 8*lane..+8
                uint4 hA1 = h4[64 + lane];            // b0, k = 512+8*lane..+8
                uint4 hB0 = h4[256 + lane];           // b1
                uint4 hB1 = h4[256 + 64 + lane];
#pragma unroll
                for (int rr = 0; rr < 8; ++rr) {
                    const int wb = (w * 8 + rr) * 128;
                    uint4 w0 = w4p[wb + lane];        // k = 8*lane..+8
                    uint4 w1 = w4p[wb + 64 + lane];   // k = 512+8*lane..+8
                    acc[rr][0] = dot8(w0, hA0, acc[rr][0]);
                    acc[rr][0] = dot8(w1, hA1, acc[rr][0]);
                    acc[rr][1] = dot8(w0, hB0, acc[rr][1]);
                    acc[rr][1] = dot8(w1, hB1, acc[rr][1]);
                }
            }

            // ---- k >= 1024: W fp32 from L2, r13-exact structure ----
#pragma unroll
            for (int c = 2; c < 4; ++c) {
                const int gr = c * 64 + lane;        // granule 128..255 (8 k)
                uint4 q0 = h4[gr];                   // batch b0
                uint4 q1 = h4[256 + gr];             // batch b0+1
                float a0 = f16lo(q0.x), a1 = f16hi(q0.x);
                float a2 = f16lo(q0.y), a3 = f16hi(q0.y);
                float a4 = f16lo(q0.z), a5 = f16hi(q0.z);
                float a6 = f16lo(q0.w), a7 = f16hi(q0.w);
                float c0 = f16lo(q1.x), c1 = f16hi(q1.x);
                float c2 = f16lo(q1.y), c3 = f16hi(q1.y);
                float c4 = f16lo(q1.z), c5 = f16hi(q1.z);
                float c6 = f16lo(q1.w), c7 = f16hi(q1.w);
#pragma unroll
                for (int rr = 0; rr < 8; ++rr) {
                    const float4* Wp = W4 + (size_t)(rbase + rr) * (RDIM / 4) + gr * 2;
                    float4 w0 = Wp[0];
                    float4 w1 = Wp[1];
                    acc[rr][0] += w0.x * a0 + w0.y * a1 + w0.z * a2 + w0.w * a3
                                + w1.x * a4 + w1.y * a5 + w1.z * a6 + w1.w * a7;
                    acc[rr][1] += w0.x * c0 + w0.y * c1 + w0.z * c2 + w0.w * c3
                                + w1.x * c4 + w1.y * c5 + w1.z * c6 + w1.w * c7;
                }
            }

            // ---- reduce: fold 32, swizzled transpose, sum 32 partials ----
            float v[16];
#pragma unroll
            for (int i = 0; i < 16; ++i) {
                float a = acc[i >> 1][i & 1];
                v[i] = a + __shfl_xor(a, 32, 64);
            }
            if (lane < 32) {
#pragma unroll
                for (int i = 0; i < 16; ++i)
                    red[w][lane * 17 + ((i + lane) & 15)] = v[i];
            }
            __syncthreads();
            if (lane < 16) {
                float s = 0.f;
#pragma unroll
                for (int l = 0; l < 32; ++l)
                    s += red[w][l * 17 + ((lane + l) & 15)];
                const int r   = lane >> 1;          // 0..7
                const int b   = lane & 1;
                const int row = rbase + r;
                const int bg  = b0 + b;
                float pre = s;
#pragma unroll
                for (int c = 0; c < NIN; ++c)
                    pre += Win[row * NIN + c] * x[((size_t)bg * TSTEPS + t) * NIN + c];
                hblk[w * 8 + r][b] = tanhf(pre);
            }
            __syncthreads();   // hblk complete

            // ---- write h_new strips (UC) + flag, r8-exact discipline ----
            if (w == 0) {
                const int b = lane >> 5;            // 0..1
                const int j = lane & 31;            // dword within 64-row strip
                sysst(&hnext[(size_t)(b0 + b) * (RDIM / 2) + rg * 32 + j],
                      packf16(hblk[2 * j][b], hblk[2 * j + 1][b]));
                __builtin_amdgcn_s_waitcnt(0);      // strips visible first
            }
            __syncthreads();
            if (tid == 0) sysst(&flags[g * 32 + rg], (unsigned)(t + 1));
        }

        // ---- projection of h_{t-1}-state (in hs) by rotating block ----
        if (t > 0 && rg == ((t - 1) & 31)) {
            const unsigned short* hsv = (const unsigned short*)hs_dw;
            const int o = t - 1;
            if (w < 6) {
                const int b = w / NOUT;             // 0..1
                const int k = w % NOUT;             // 0..2
                float a = 0.f;
#pragma unroll
                for (int j = 0; j < 32; ++j) {
                    const int r = j * 64 + lane;
                    a += f16s(hsv[b * RDIM + r]) * Wout[k * RDIM + r];
                }
#pragma unroll
                for (int off = 32; off >= 1; off >>= 1)
                    a += __shfl_xor(a, off, 64);
                if (lane == 0)
                    out[((size_t)(b0 + b) * TSTEPS + o) * NOUT + k] = a + bout[k];
            }
        }
    }
}

extern "C" void kernel_launch(void* const* d_in, const int* in_sizes, int n_in,
                              void* d_out, int out_size, void* d_ws, size_t ws_size,
                              hipStream_t stream) {
    const float* x    = (const float*)d_in[0];
    const float* Win  = (const float*)d_in[1];
    const float* W    = (const float*)d_in[2];
    const float* Wout = (const float*)d_in[3];
    const float* bout = (const float*)d_in[4];
    float* out = (float*)d_out;

    unsigned* wsu   = (unsigned*)d_ws;
    unsigned* hb0   = wsu + OFF_H0;
    unsigned* hb1   = wsu + OFF_H1;
    unsigned* flags = wsu + OFF_FLAGS;

    // zero h buffers + flags (~132 KB)
    hipMemsetAsync(d_ws, 0, (size_t)WS_USED * sizeof(unsigned), stream);

    // allow 128 KB dynamic LDS (idempotent; same work every call)
    hipFuncSetAttribute((const void*)esn_persist,
                        hipFuncAttributeMaxDynamicSharedMemorySize, 131072);

    void* args[] = {(void*)&W, (void*)&Win, (void*)&x, (void*)&Wout, (void*)&bout,
                    (void*)&hb0, (void*)&hb1, (void*)&flags, (void*)&out};
    hipError_t e = hipLaunchCooperativeKernel((const void*)esn_persist,
                                              dim3(NBLK), dim3(NTHR),
                                              args, 131072, stream);
    if (e != hipSuccess) {
        // Fallback: plain launch (256 blocks, 1/CU with 154KB LDS -> all
        // co-resident; bounded spins guarantee no hang regardless).
        esn_persist<<<dim3(NBLK), dim3(NTHR), 131072, stream>>>(
            W, Win, x, Wout, bout, hb0, hb1, flags, out);
    }
}

// Round 16
// 7648.422 us; speedup vs baseline: 1.7784x; 1.4762x over previous
//
#include <hip/hip_runtime.h>
#include <math.h>

// ESN reservoir, persistent kernel, round 16.
// h_t = tanh(x_t Win^T + h_{t-1} W^T); out_t = h_t Wout^T + b
//
// r13 budget (10.49ms): gate 0.8 + stage 1.2 + max(W-L2 1.9, VALU 1.7) + 0.5.
// r15 proved LDS conflicts are latency-hidden (not on critical path).
// Round 16 removes BOTH big terms via int8:
//  - ALL of the block's W (64 rows x 2048) in 128KB dynamic LDS as int8,
//    per-row scale (rel err ~0.4%; W zeros stay 0). No more L2-W stream.
//  - h exchanged as int8 (scale 127, |h|<=1): exchange 2MB -> 1MB/step.
//  - v_dot4_i32_i8 (sdot4): 4 MAC/inst, exact int32 accumulate, dequant
//    once per row in epilogue. Fallback = exact same math via byte extract.
//  - gate/stage/flag discipline r13-exact; bounded spins: never hangs.

#define RDIM   2048
#define BATCH  16
#define TSTEPS 2048
#define NIN    3
#define NOUT   3
#define NBLK   256
#define NTHR   512

#define HB_BYTES  (BATCH * RDIM)             // 32 KB per h buffer (int8)
#define OFF_H0_B  0
#define OFF_H1_B  (HB_BYTES)
#define OFF_FLAGS ((2 * HB_BYTES) / 4)       // dword index: 256 dwords
#define WS_USED_DW (OFF_FLAGS + 256)
#define WLDS_DW   (64 * 512)                 // 32768 dwords = 128 KB int8 W
#define SPIN_MAX  (1L << 20)

#define CPOL_SC0_SC1 0x11                    // UC: read at coherence point

__device__ __forceinline__ void load_lds16(const void* g, void* l) {
    __builtin_amdgcn_global_load_lds(
        (const __attribute__((address_space(1))) void*)g,
        (__attribute__((address_space(3))) void*)l, 16, 0, CPOL_SC0_SC1);
}

__device__ __forceinline__ unsigned sysld(const unsigned* p) {
    return __hip_atomic_load(p, __ATOMIC_RELAXED, __HIP_MEMORY_SCOPE_SYSTEM);
}
__device__ __forceinline__ void sysst(unsigned* p, unsigned v) {
    __hip_atomic_store(p, v, __ATOMIC_RELAXED, __HIP_MEMORY_SCOPE_SYSTEM);
}

__device__ __forceinline__ int q8(float v) {          // round, clamp [-127,127]
    float c = fminf(127.f, fmaxf(-127.f, v));
    return (int)__builtin_rintf(c);
}
__device__ __forceinline__ unsigned pack4(int a, int b, int c, int d) {
    return (a & 0xff) | ((b & 0xff) << 8) | ((c & 0xff) << 16) | ((d & 0xff) << 24);
}

// dword(4xi8) dot dword(4xi8) + c, exact int32
__device__ __forceinline__ int dot4i(unsigned a, unsigned b, int c) {
#if __has_builtin(__builtin_amdgcn_sdot4)
    return __builtin_amdgcn_sdot4((int)a, (int)b, c, false);
#else
    c += (int)(signed char)(a) * (int)(signed char)(b);
    c += (int)(signed char)(a >> 8)  * (int)(signed char)(b >> 8);
    c += (int)(signed char)(a >> 16) * (int)(signed char)(b >> 16);
    c += (int)(signed char)(a >> 24) * (int)(signed char)(b >> 24);
    return c;
#endif
}
// 16-element int8 dot via uint4 (4 sdot4)
__device__ __forceinline__ int dot16(uint4 wq, uint4 hq, int c) {
    c = dot4i(wq.x, hq.x, c);
    c = dot4i(wq.y, hq.y, c);
    c = dot4i(wq.z, hq.z, c);
    c = dot4i(wq.w, hq.w, c);
    return c;
}

extern "C" __global__ void __launch_bounds__(NTHR, 1) esn_persist(
    const float* __restrict__ W,       // [R,R] fp32
    const float* __restrict__ Win,     // [R,3]
    const float* __restrict__ x,       // [B,T,3]
    const float* __restrict__ Wout,    // [3,R]
    const float* __restrict__ bout,    // [3]
    unsigned char* hb0,                // [B][R] int8 (scale 1/127)
    unsigned char* hb1,
    unsigned* flags,                   // [256]
    float* __restrict__ out)           // [B,T,3]
{
    __shared__ unsigned hs_dw[1024];            // 4 KB: staged h int8 [2][2048B]
    __shared__ int  red[8][544];                // transpose-reduce (int partials)
    __shared__ float hblk[64][2];               // 64 rows x 2 batches (float)
    __shared__ float wscale[64];                // per-row W scale (m/127)
    extern __shared__ unsigned wlds[];          // 128 KB: W int8 [64 rows][512 dw]

    const int tid  = threadIdx.x;
    const int lane = tid & 63;
    const int w    = tid >> 6;                  // wave 0..7
    const int blk  = blockIdx.x;
    const int rg   = blk & 31;                  // rows rg*64..+64
    const int g    = blk >> 5;                  // batches g*2..+2
    const int rbase = rg * 64 + w * 8;          // wave's 8 rows
    const int b0    = g * 2;

    // ---- one-time: quantize W rows -> LDS int8 (per-row scale) ----
#pragma unroll
    for (int rr = 0; rr < 8; ++rr) {
        const int   row = rbase + rr;
        const float4* Wr = (const float4*)(W + (size_t)row * RDIM);
        float m = 0.f;
#pragma unroll
        for (int j = 0; j < 8; ++j) {           // lane covers 8 float4 = 32 elems
            float4 v = Wr[j * 64 + lane];
            m = fmaxf(m, fmaxf(fmaxf(fabsf(v.x), fabsf(v.y)),
                               fmaxf(fabsf(v.z), fabsf(v.w))));
        }
#pragma unroll
        for (int off = 32; off >= 1; off >>= 1)
            m = fmaxf(m, __shfl_xor(m, off, 64));
        const float inv = (m > 0.f) ? 127.f / m : 0.f;
        if (lane == 0) wscale[w * 8 + rr] = (m > 0.f) ? m / 127.f : 0.f;
#pragma unroll
        for (int j = 0; j < 8; ++j) {
            float4 v = Wr[j * 64 + lane];
            wlds[(w * 8 + rr) * 512 + j * 64 + lane] =
                pack4(q8(v.x * inv), q8(v.y * inv), q8(v.z * inv), q8(v.w * inv));
        }
    }
    __syncthreads();

    for (int t = 0; t <= TSTEPS; ++t) {
        const unsigned char* hprev = (t & 1) ? hb1 : hb0;
        unsigned char*       hnext = (t & 1) ? hb0 : hb1;
        const unsigned       tgt   = (unsigned)t;

        // ---- one-hop gate: all 32 producers of my group at >= t ----
        if (t > 0 && w == 0) {
            long spins = 0;
            for (;;) {
                unsigned vv = (lane < 32) ? sysld(&flags[g * 32 + lane]) : tgt;
                if (__all((int)(vv >= tgt))) break;
                if (spins > 64) __builtin_amdgcn_s_sleep(2);  // fast-poll first
                if (++spins > SPIN_MAX) break;   // never hang
            }
        }
        __syncthreads();

        // ---- stage h[b0..b0+1][:] int8 (4 KB = 256 granules), waves 0-3 ----
        if (w < 4) {
            load_lds16(hprev + (size_t)g * 4096 + (size_t)(w * 64 + lane) * 16,
                       (char*)hs_dw + (size_t)(w * 64) * 16);
        }
        __syncthreads();   // staging complete (drains vmcnt)

        if (t < TSTEPS) {
            int acc[8][2];
#pragma unroll
            for (int r = 0; r < 8; ++r) { acc[r][0] = 0; acc[r][1] = 0; }

            // h granules: batch b0 at 0..127, b1 at 128..255 (16 k each)
            const uint4* h4 = (const uint4*)hs_dw;
            uint4 hA0 = h4[lane];            // b0, k = 16*lane..+16
            uint4 hA1 = h4[64 + lane];       // b0, k = 1024+16*lane..+16
            uint4 hB0 = h4[128 + lane];      // b1
            uint4 hB1 = h4[192 + lane];

            const uint4* w4p = (const uint4*)wlds;   // row r: 128 granules
#pragma unroll
            for (int rr = 0; rr < 8; ++rr) {
                const int wb = (w * 8 + rr) * 128;
                uint4 w0 = w4p[wb + lane];           // k = 16*lane..+16
                uint4 w1 = w4p[wb + 64 + lane];      // k = 1024+16*lane..+16
                acc[rr][0] = dot16(w0, hA0, acc[rr][0]);
                acc[rr][0] = dot16(w1, hA1, acc[rr][0]);
                acc[rr][1] = dot16(w0, hB0, acc[rr][1]);
                acc[rr][1] = dot16(w1, hB1, acc[rr][1]);
            }

            // ---- reduce: fold 32, swizzled transpose, sum 32 (int exact) ----
            int v[16];
#pragma unroll
            for (int i = 0; i < 16; ++i) {
                int a = acc[i >> 1][i & 1];
                v[i] = a + __shfl_xor(a, 32, 64);
            }
            if (lane < 32) {
#pragma unroll
                for (int i = 0; i < 16; ++i)
                    red[w][lane * 17 + ((i + lane) & 15)] = v[i];
            }
            __syncthreads();
            if (lane < 16) {
                int s = 0;
#pragma unroll
                for (int l = 0; l < 32; ++l)
                    s += red[w][l * 17 + ((lane + l) & 15)];
                const int r   = lane >> 1;          // 0..7
                const int b   = lane & 1;
                const int row = rbase + r;
                const int bg  = b0 + b;
                // dequant: W ~ wq*s_r, h ~ hq/127
                float pre = (float)s * wscale[w * 8 + r] * (1.f / 127.f);
#pragma unroll
                for (int c = 0; c < NIN; ++c)
                    pre += Win[row * NIN + c] * x[((size_t)bg * TSTEPS + t) * NIN + c];
                hblk[w * 8 + r][b] = tanhf(pre);
            }
            __syncthreads();   // hblk complete

            // ---- write h_new strips int8 (UC) + flag, r8-exact discipline ----
            if (w == 0) {
                if (lane < 32) {
                    const int b = lane >> 4;        // 0..1
                    const int j = lane & 15;        // dword: rows 4j..4j+3
                    unsigned p = pack4(q8(hblk[4 * j][b] * 127.f),
                                       q8(hblk[4 * j + 1][b] * 127.f),
                                       q8(hblk[4 * j + 2][b] * 127.f),
                                       q8(hblk[4 * j + 3][b] * 127.f));
                    sysst((unsigned*)(hnext + (size_t)(b0 + b) * RDIM + rg * 64) + j, p);
                }
                __builtin_amdgcn_s_waitcnt(0);      // strips visible first
            }
            __syncthreads();
            if (tid == 0) sysst(&flags[g * 32 + rg], (unsigned)(t + 1));
        }

        // ---- projection of h_{t-1}-state (int8 in hs) by rotating block ----
        if (t > 0 && rg == ((t - 1) & 31)) {
            const signed char* hsv = (const signed char*)hs_dw;
            const int o = t - 1;
            if (w < 6) {
                const int b = w / NOUT;             // 0..1
                const int k = w % NOUT;             // 0..2
                float a = 0.f;
#pragma unroll
                for (int j = 0; j < 32; ++j) {
                    const int r = j * 64 + lane;
                    a += (float)hsv[b * RDIM + r] * Wout[k * RDIM + r];
                }
#pragma unroll
                for (int off = 32; off >= 1; off >>= 1)
                    a += __shfl_xor(a, off, 64);
                if (lane == 0)
                    out[((size_t)(b0 + b) * TSTEPS + o) * NOUT + k] =
                        a * (1.f / 127.f) + bout[k];
            }
        }
    }
}

extern "C" void kernel_launch(void* const* d_in, const int* in_sizes, int n_in,
                              void* d_out, int out_size, void* d_ws, size_t ws_size,
                              hipStream_t stream) {
    const float* x    = (const float*)d_in[0];
    const float* Win  = (const float*)d_in[1];
    const float* W    = (const float*)d_in[2];
    const float* Wout = (const float*)d_in[3];
    const float* bout = (const float*)d_in[4];
    float* out = (float*)d_out;

    unsigned char* wsb = (unsigned char*)d_ws;
    unsigned char* hb0 = wsb + OFF_H0_B;
    unsigned char* hb1 = wsb + OFF_H1_B;
    unsigned*    flags = (unsigned*)d_ws + OFF_FLAGS;

    // zero h buffers (h0 = 0 in int8 too) + flags (~66 KB)
    hipMemsetAsync(d_ws, 0, (size_t)WS_USED_DW * sizeof(unsigned), stream);

    // allow 128 KB dynamic LDS (idempotent; same work every call)
    hipFuncSetAttribute((const void*)esn_persist,
                        hipFuncAttributeMaxDynamicSharedMemorySize, 131072);

    void* args[] = {(void*)&W, (void*)&Win, (void*)&x, (void*)&Wout, (void*)&bout,
                    (void*)&hb0, (void*)&hb1, (void*)&flags, (void*)&out};
    hipError_t e = hipLaunchCooperativeKernel((const void*)esn_persist,
                                              dim3(NBLK), dim3(NTHR),
                                              args, 131072, stream);
    if (e != hipSuccess) {
        // Fallback: plain launch (256 blocks, 1/CU with ~150KB LDS -> all
        // co-resident; bounded spins guarantee no hang regardless).
        esn_persist<<<dim3(NBLK), dim3(NTHR), 131072, stream>>>(
            W, Win, x, Wout, bout, hb0, hb1, flags, out);
    }
}